// Round 2
// baseline (715.194 us; speedup 1.0000x reference)
//
#include <hip/hip_runtime.h>

#define NN 100000
#define NE 1600000
#define NG 512
#define F  32

// ---- degree over dst (float atomics) ----
__global__ void k_deg(const int* __restrict__ dst, float* __restrict__ deg) {
    int e = blockIdx.x * blockDim.x + threadIdx.x;
    if (e < NE) atomicAdd(&deg[dst[e]], 1.0f);
}

// ---- dinv = rsqrt(deg + 1) in place ----
__global__ void k_dinv(float* __restrict__ deg) {
    int i = blockIdx.x * blockDim.x + threadIdx.x;
    if (i < NN) deg[i] = rsqrtf(deg[i] + 1.0f);
}

// ---- per-edge norm = dinv[src]*dinv[dst] ----
__global__ void k_norm(const int* __restrict__ src, const int* __restrict__ dst,
                       const float* __restrict__ dinv, float* __restrict__ norm) {
    int e = blockIdx.x * blockDim.x + threadIdx.x;
    if (e < NE) norm[e] = dinv[src[e]] * dinv[dst[e]];
}

// ---- xw1 = x @ W1  (x: [N,3], W1: [3,32]) ----
__global__ void k_xw1(const float* __restrict__ x, const float* __restrict__ W1,
                      float* __restrict__ xw) {
    int idx = blockIdx.x * blockDim.x + threadIdx.x;   // n*32 + f
    if (idx >= NN * F) return;
    int n = idx >> 5, f = idx & 31;
    float v = x[n * 3 + 0] * W1[0 * F + f]
            + x[n * 3 + 1] * W1[1 * F + f]
            + x[n * 3 + 2] * W1[2 * F + f];
    xw[idx] = v;
}

// ---- scatter: agg[dst] += xw[src] * norm[e], 32 lanes per edge ----
__global__ void k_scatter(const int* __restrict__ src, const int* __restrict__ dst,
                          const float* __restrict__ norm, const float* __restrict__ xw,
                          float* __restrict__ agg) {
    int t = blockIdx.x * blockDim.x + threadIdx.x;
    int e = t >> 5;
    int f = t & 31;
    if (e >= NE) return;
    int s = src[e];
    int d = dst[e];
    float v = xw[s * F + f] * norm[e];
    atomicAdd(&agg[d * F + f], v);
}

// ---- epilogue (in-place over agg): h = relu(agg + xw*dinv^2 + b) ----
__global__ void k_epilogue(float* __restrict__ agg, const float* __restrict__ xw,
                           const float* __restrict__ dinv, const float* __restrict__ b) {
    int idx = blockIdx.x * blockDim.x + threadIdx.x;
    if (idx >= NN * F) return;
    int n = idx >> 5, f = idx & 31;
    float di = dinv[n];
    float v = agg[idx] + xw[idx] * (di * di) + b[f];
    agg[idx] = fmaxf(v, 0.0f);
}

// ---- xw2 = h @ W2  (h: [N,32], W2: [32,32]); 8 nodes per 256-thread block ----
__global__ void k_xw2(const float* __restrict__ h, const float* __restrict__ W2,
                      float* __restrict__ xw) {
    __shared__ float Ws[F * F];
    __shared__ float hs[8][F];
    int tid = threadIdx.x;
    for (int i = tid; i < F * F; i += 256) Ws[i] = W2[i];
    int nl = tid >> 5, f = tid & 31;
    int n = blockIdx.x * 8 + nl;
    if (n < NN) hs[nl][f] = h[n * F + f];
    __syncthreads();
    if (n >= NN) return;
    float acc = 0.0f;
#pragma unroll
    for (int k = 0; k < F; k++) acc += hs[nl][k] * Ws[k * F + f];
    xw[n * F + f] = acc;
}

// ---- pool: gsum[batch[n]] += h[n], gcnt[batch[n]] += 1 ----
__global__ void k_pool(const float* __restrict__ h, const int* __restrict__ batch,
                       float* __restrict__ gsum, float* __restrict__ gcnt) {
    int idx = blockIdx.x * blockDim.x + threadIdx.x;
    if (idx >= NN * F) return;
    int n = idx >> 5, f = idx & 31;
    int b = batch[n];
    atomicAdd(&gsum[b * F + f], h[idx]);
    if (f == 0) atomicAdd(&gcnt[b], 1.0f);
}

// ---- head: out[g,o] = (gsum[g]/max(cnt,1)) @ Wl + bl ----
__global__ void k_final(const float* __restrict__ gsum, const float* __restrict__ gcnt,
                        const float* __restrict__ Wl, const float* __restrict__ bl,
                        float* __restrict__ out) {
    int idx = blockIdx.x * blockDim.x + threadIdx.x;   // g*2 + o
    if (idx >= NG * 2) return;
    int g = idx >> 1, o = idx & 1;
    float cnt = fmaxf(gcnt[g], 1.0f);
    float acc = 0.0f;
#pragma unroll
    for (int k = 0; k < F; k++) acc += gsum[g * F + k] * Wl[k * 2 + o];
    out[idx] = acc / cnt + bl[o];
}

extern "C" void kernel_launch(void* const* d_in, const int* in_sizes, int n_in,
                              void* d_out, int out_size, void* d_ws, size_t ws_size,
                              hipStream_t stream) {
    const float* x     = (const float*)d_in[0];
    const int*   eidx  = (const int*)d_in[1];    // int32 per harness contract
    const int*   batch = (const int*)d_in[2];    // int32 per harness contract
    const float* W1    = (const float*)d_in[3];
    const float* b1    = (const float*)d_in[4];
    const float* W2    = (const float*)d_in[5];
    const float* b2    = (const float*)d_in[6];
    const float* Wl    = (const float*)d_in[7];
    const float* bl    = (const float*)d_in[8];
    float*       out   = (float*)d_out;

    const int* src = eidx;
    const int* dst = eidx + NE;

    // workspace layout (floats): dinv[NN] | norm[NE] | buf1[NN*F] | buf2[NN*F] | gsum[NG*F] | gcnt[NG]
    float* ws   = (float*)d_ws;
    float* dinv = ws;
    float* norm = dinv + NN;
    float* buf1 = norm + NE;                  // xw (both layers)
    float* buf2 = buf1 + (size_t)NN * F;      // agg -> h (in-place epilogue)
    float* gsum = buf2 + (size_t)NN * F;
    float* gcnt = gsum + (size_t)NG * F;

    const int B = 256;
    const int gEdge = (NE + B - 1) / B;       // 6250
    const int gNode = (NN + B - 1) / B;       // 391
    const int gNF   = (NN * F + B - 1) / B;   // 12500
    const int gScat = ((size_t)NE * F + B - 1) / B; // 200000
    const int gXw2  = (NN + 7) / 8;           // 12500

    // degree + dinv + norm (shared by both layers)
    hipMemsetAsync(dinv, 0, NN * sizeof(float), stream);
    k_deg<<<gEdge, B, 0, stream>>>(dst, dinv);
    k_dinv<<<gNode, B, 0, stream>>>(dinv);
    k_norm<<<gEdge, B, 0, stream>>>(src, dst, dinv, norm);

    // ---- layer 1 ----
    k_xw1<<<gNF, B, 0, stream>>>(x, W1, buf1);
    hipMemsetAsync(buf2, 0, (size_t)NN * F * sizeof(float), stream);
    k_scatter<<<gScat, B, 0, stream>>>(src, dst, norm, buf1, buf2);
    k_epilogue<<<gNF, B, 0, stream>>>(buf2, buf1, dinv, b1);   // buf2 = h1

    // ---- layer 2 ----
    k_xw2<<<gXw2, B, 0, stream>>>(buf2, W2, buf1);             // buf1 = h1@W2
    hipMemsetAsync(buf2, 0, (size_t)NN * F * sizeof(float), stream);
    k_scatter<<<gScat, B, 0, stream>>>(src, dst, norm, buf1, buf2);
    k_epilogue<<<gNF, B, 0, stream>>>(buf2, buf1, dinv, b2);   // buf2 = h2

    // ---- pool + head ----
    hipMemsetAsync(gsum, 0, ((size_t)NG * F + NG) * sizeof(float), stream);
    k_pool<<<gNF, B, 0, stream>>>(buf2, batch, gsum, gcnt);
    k_final<<<(NG * 2 + B - 1) / B, B, 0, stream>>>(gsum, gcnt, Wl, bl, out);
}

// Round 3
// 441.798 us; speedup vs baseline: 1.6188x; 1.6188x over previous
//
#include <hip/hip_runtime.h>

#define NN 100000
#define NE 1600000
#define NG 512
#define F  32

// ================= CSR build =================

__global__ void k_deg(const int* __restrict__ dst, int* __restrict__ deg) {
    int e = blockIdx.x * blockDim.x + threadIdx.x;
    if (e < NE) atomicAdd(&deg[dst[e]], 1);
}

// exclusive scan of deg[NN] -> row[NN] (+ block sums). 1024 elems/block.
__global__ void k_scan1(const int* __restrict__ deg, int* __restrict__ row,
                        int* __restrict__ bsum) {
    __shared__ int lds[256];
    int tid = threadIdx.x;
    int base = blockIdx.x * 1024 + tid * 4;
    int v0 = (base + 0 < NN) ? deg[base + 0] : 0;
    int v1 = (base + 1 < NN) ? deg[base + 1] : 0;
    int v2 = (base + 2 < NN) ? deg[base + 2] : 0;
    int v3 = (base + 3 < NN) ? deg[base + 3] : 0;
    int s = v0 + v1 + v2 + v3;
    lds[tid] = s;
    __syncthreads();
    for (int off = 1; off < 256; off <<= 1) {
        int t = (tid >= off) ? lds[tid - off] : 0;
        __syncthreads();
        lds[tid] += t;
        __syncthreads();
    }
    int excl = lds[tid] - s;
    if (tid == 255) bsum[blockIdx.x] = lds[255];
    if (base + 0 < NN) row[base + 0] = excl;
    if (base + 1 < NN) row[base + 1] = excl + v0;
    if (base + 2 < NN) row[base + 2] = excl + v0 + v1;
    if (base + 3 < NN) row[base + 3] = excl + v0 + v1 + v2;
}

// exclusive scan of the 98 block sums, in place. one block of 128.
__global__ void k_scan2(int* __restrict__ bsum, int nb) {
    __shared__ int lds[128];
    int tid = threadIdx.x;
    int v = (tid < nb) ? bsum[tid] : 0;
    lds[tid] = v;
    __syncthreads();
    for (int off = 1; off < 128; off <<= 1) {
        int t = (tid >= off) ? lds[tid - off] : 0;
        __syncthreads();
        lds[tid] += t;
        __syncthreads();
    }
    if (tid < nb) bsum[tid] = lds[tid] - v;
}

__global__ void k_scan3(int* __restrict__ row, const int* __restrict__ bsum) {
    int i = blockIdx.x * blockDim.x + threadIdx.x;
    if (i < NN) row[i] += bsum[i >> 10];
    if (i == 0) row[NN] = NE;
}

// dinv = rsqrt(deg+1)
__global__ void k_dinv(const int* __restrict__ deg, float* __restrict__ dinv) {
    int i = blockIdx.x * blockDim.x + threadIdx.x;
    if (i < NN) dinv[i] = rsqrtf((float)deg[i] + 1.0f);
}

// fill csr_src sorted by dst (cnt must be zeroed; order within segment arbitrary)
__global__ void k_fill(const int* __restrict__ src, const int* __restrict__ dst,
                       const int* __restrict__ row, int* __restrict__ cnt,
                       int* __restrict__ csr_src) {
    int e = blockIdx.x * blockDim.x + threadIdx.x;
    if (e >= NE) return;
    int d = dst[e];
    int pos = row[d] + atomicAdd(&cnt[d], 1);
    csr_src[pos] = src[e];
}

// ================= layers =================

// layer1 gather, fused x@W1 + self-loop + bias + relu.
// 32 lanes per node (8 nodes / 256-block), lane f = feature.
__global__ void k_gather1(const int* __restrict__ row, const int* __restrict__ csr,
                          const float* __restrict__ x, const float* __restrict__ dinv,
                          const float* __restrict__ W1, const float* __restrict__ b1,
                          float* __restrict__ h) {
    int tid = threadIdx.x;
    int n = blockIdx.x * 8 + (tid >> 5);
    if (n >= NN) return;
    int f = tid & 31;
    float w0 = W1[0 * F + f], w1 = W1[1 * F + f], w2 = W1[2 * F + f];
    int beg = row[n], end = row[n + 1];
    float acc = 0.0f;
    for (int e = beg; e < end; ++e) {
        int s = csr[e];
        float di = dinv[s];
        float xv = x[s * 3 + 0] * w0 + x[s * 3 + 1] * w1 + x[s * 3 + 2] * w2;
        acc += di * xv;
    }
    float dn = dinv[n];
    float self = x[n * 3 + 0] * w0 + x[n * 3 + 1] * w1 + x[n * 3 + 2] * w2;
    float v = dn * acc + self * (dn * dn) + b1[f];
    h[n * F + f] = fmaxf(v, 0.0f);
}

// xw2 = h @ W2  (h: [N,32], W2: [32,32]); 8 nodes per 256-thread block
__global__ void k_xw2(const float* __restrict__ h, const float* __restrict__ W2,
                      float* __restrict__ xw) {
    __shared__ float Ws[F * F];
    __shared__ float hs[8][F];
    int tid = threadIdx.x;
    for (int i = tid; i < F * F; i += 256) Ws[i] = W2[i];
    int nl = tid >> 5, f = tid & 31;
    int n = blockIdx.x * 8 + nl;
    if (n < NN) hs[nl][f] = h[n * F + f];
    __syncthreads();
    if (n >= NN) return;
    float acc = 0.0f;
#pragma unroll
    for (int k = 0; k < F; k++) acc += hs[nl][k] * Ws[k * F + f];
    xw[n * F + f] = acc;
}

// layer2 gather + self-loop + bias + relu
__global__ void k_gather2(const int* __restrict__ row, const int* __restrict__ csr,
                          const float* __restrict__ xw, const float* __restrict__ dinv,
                          const float* __restrict__ b2, float* __restrict__ h) {
    int tid = threadIdx.x;
    int n = blockIdx.x * 8 + (tid >> 5);
    if (n >= NN) return;
    int f = tid & 31;
    int beg = row[n], end = row[n + 1];
    float acc = 0.0f;
    for (int e = beg; e < end; ++e) {
        int s = csr[e];
        acc += dinv[s] * xw[s * F + f];
    }
    float dn = dinv[n];
    float v = dn * acc + xw[n * F + f] * (dn * dn) + b2[f];
    h[n * F + f] = fmaxf(v, 0.0f);
}

// ================= pool + head =================
// one block per graph; batch is sorted -> binary search the node range.
__global__ void k_pool_head(const float* __restrict__ h, const int* __restrict__ batch,
                            const float* __restrict__ Wl, const float* __restrict__ bl,
                            float* __restrict__ out) {
    __shared__ float sum[8][F];
    __shared__ float mean[F];
    __shared__ int range[2];
    int g = blockIdx.x, tid = threadIdx.x;
    if (tid < 2) {
        int key = g + tid, lo = 0, hi = NN;
        while (lo < hi) {
            int mid = (lo + hi) >> 1;
            if (batch[mid] < key) lo = mid + 1; else hi = mid;
        }
        range[tid] = lo;
    }
    __syncthreads();
    int s = range[0], e = range[1];
    int grp = tid >> 5, f = tid & 31;
    float acc = 0.0f;
    for (int n = s + grp; n < e; n += 8) acc += h[n * F + f];
    sum[grp][f] = acc;
    __syncthreads();
    if (grp == 0) {
        float t = sum[0][f] + sum[1][f] + sum[2][f] + sum[3][f]
                + sum[4][f] + sum[5][f] + sum[6][f] + sum[7][f];
        mean[f] = t / fmaxf((float)(e - s), 1.0f);
    }
    __syncthreads();
    if (tid < 2) {
        float a = 0.0f;
#pragma unroll
        for (int k = 0; k < F; k++) a += mean[k] * Wl[k * 2 + tid];
        out[g * 2 + tid] = a + bl[tid];
    }
}

extern "C" void kernel_launch(void* const* d_in, const int* in_sizes, int n_in,
                              void* d_out, int out_size, void* d_ws, size_t ws_size,
                              hipStream_t stream) {
    const float* x     = (const float*)d_in[0];
    const int*   eidx  = (const int*)d_in[1];   // int32 per harness contract
    const int*   batch = (const int*)d_in[2];
    const float* W1    = (const float*)d_in[3];
    const float* b1    = (const float*)d_in[4];
    const float* W2    = (const float*)d_in[5];
    const float* b2    = (const float*)d_in[6];
    const float* Wl    = (const float*)d_in[7];
    const float* bl    = (const float*)d_in[8];
    float*       out   = (float*)d_out;

    const int* src = eidx;
    const int* dst = eidx + NE;

    // ws layout (4B units):
    // deg/cnt[NN] | row[NN+1] | bsum[128] | csr[NE] | dinv[NN] | buf1[NN*F] | buf2[NN*F]
    int*   deg  = (int*)d_ws;
    int*   row  = deg + NN;
    int*   bsum = row + (NN + 1);
    int*   csr  = bsum + 128;
    float* dinv = (float*)(csr + NE);
    float* buf1 = dinv + NN;
    float* buf2 = buf1 + (size_t)NN * F;

    const int B = 256;
    const int gEdge = (NE + B - 1) / B;           // 6250
    const int gNode = (NN + B - 1) / B;           // 391
    const int gGath = (NN + 7) / 8;               // 12500
    const int nbScan = (NN + 1023) / 1024;        // 98

    // ---- CSR build (shared by both layers) ----
    hipMemsetAsync(deg, 0, NN * sizeof(int), stream);
    k_deg<<<gEdge, B, 0, stream>>>(dst, deg);
    k_scan1<<<nbScan, 256, 0, stream>>>(deg, row, bsum);
    k_scan2<<<1, 128, 0, stream>>>(bsum, nbScan);
    k_scan3<<<gNode, B, 0, stream>>>(row, bsum);
    k_dinv<<<gNode, B, 0, stream>>>(deg, dinv);
    hipMemsetAsync(deg, 0, NN * sizeof(int), stream);   // deg becomes fill cursor
    k_fill<<<gEdge, B, 0, stream>>>(src, dst, row, deg, csr);

    // ---- layer 1 (fused transform+aggregate+epilogue) ----
    k_gather1<<<gGath, B, 0, stream>>>(row, csr, x, dinv, W1, b1, buf2);  // buf2 = h1

    // ---- layer 2 ----
    k_xw2<<<gGath, B, 0, stream>>>(buf2, W2, buf1);                      // buf1 = h1@W2
    k_gather2<<<gGath, B, 0, stream>>>(row, csr, buf1, dinv, b2, buf2);  // buf2 = h2

    // ---- pool + head ----
    k_pool_head<<<NG, B, 0, stream>>>(buf2, batch, Wl, bl, out);
}

// Round 4
// 282.927 us; speedup vs baseline: 2.5278x; 1.5615x over previous
//
#include <hip/hip_runtime.h>

#define NN 100000
#define NE 1600000
#define NG 512
#define F  32

#define BSH    9                 // 512 dst-nodes per bucket
#define BNODES 512
#define NB     ((NN + BNODES - 1) / BNODES)   // 196
#define CHUNK  16384
#define NWGE   ((NE + CHUNK - 1) / CHUNK)     // 98

// ---- per-WG LDS histogram of dst buckets -> global bucket totals ----
__global__ void k_count(const int* __restrict__ dst, int* __restrict__ btot) {
    __shared__ int hist[NB];
    int tid = threadIdx.x;
    for (int i = tid; i < NB; i += 256) hist[i] = 0;
    __syncthreads();
    int e0 = blockIdx.x * CHUNK;
    int e1 = min(e0 + CHUNK, NE);
    for (int e = e0 + tid; e < e1; e += 256) atomicAdd(&hist[dst[e] >> BSH], 1);
    __syncthreads();
    for (int i = tid; i < NB; i += 256)
        if (hist[i]) atomicAdd(&btot[i], hist[i]);
}

// ---- scan bucket totals -> bucket_start[NB+1]; init cursors ----
__global__ void k_bscan(const int* __restrict__ btot, int* __restrict__ bstart,
                        int* __restrict__ cursor) {
    __shared__ int lds[256];
    int tid = threadIdx.x;
    int v = (tid < NB) ? btot[tid] : 0;
    lds[tid] = v;
    __syncthreads();
    for (int o = 1; o < 256; o <<= 1) {
        int t = (tid >= o) ? lds[tid - o] : 0;
        __syncthreads();
        lds[tid] += t;
        __syncthreads();
    }
    int excl = lds[tid] - v;
    if (tid < NB) { bstart[tid] = excl; cursor[tid] = excl; }
    if (tid == 0) bstart[NB] = NE;
}

// ---- partition edges into bucket-contiguous (src,dst) pairs ----
__global__ void k_partition(const int* __restrict__ src, const int* __restrict__ dst,
                            int* __restrict__ cursor, int2* __restrict__ part) {
    __shared__ int hist[NB];
    __shared__ int base[NB];
    int tid = threadIdx.x;
    for (int i = tid; i < NB; i += 256) hist[i] = 0;
    __syncthreads();
    int e0 = blockIdx.x * CHUNK;
    int e1 = min(e0 + CHUNK, NE);
    for (int e = e0 + tid; e < e1; e += 256) atomicAdd(&hist[dst[e] >> BSH], 1);
    __syncthreads();
    for (int i = tid; i < NB; i += 256) {
        base[i] = hist[i] ? atomicAdd(&cursor[i], hist[i]) : 0;
        hist[i] = 0;
    }
    __syncthreads();
    for (int e = e0 + tid; e < e1; e += 256) {
        int d = dst[e];
        int b = d >> BSH;
        int p = base[b] + atomicAdd(&hist[b], 1);
        part[p] = make_int2(src[e], d);
    }
}

// ---- per-bucket: local histogram+scan -> row/dinv; scatter csr in L2-resident region ----
__global__ void k_fill2(const int2* __restrict__ part, const int* __restrict__ bstart,
                        int* __restrict__ row, float* __restrict__ dinv,
                        int* __restrict__ csr) {
    __shared__ int cnt[BNODES];
    __shared__ int off[BNODES];
    __shared__ int lds[256];
    int b = blockIdx.x, tid = threadIdx.x;
    int node0 = b << BSH;
    int s0 = bstart[b], s1 = bstart[b + 1];
    cnt[tid] = 0; cnt[tid + 256] = 0;
    __syncthreads();
    for (int i = s0 + tid; i < s1; i += 256) atomicAdd(&cnt[part[i].y - node0], 1);
    __syncthreads();
    int c0 = cnt[2 * tid], c1 = cnt[2 * tid + 1], s = c0 + c1;
    lds[tid] = s;
    __syncthreads();
    for (int o = 1; o < 256; o <<= 1) {
        int t = (tid >= o) ? lds[tid - o] : 0;
        __syncthreads();
        lds[tid] += t;
        __syncthreads();
    }
    int excl = lds[tid] - s;
    off[2 * tid] = excl;
    off[2 * tid + 1] = excl + c0;
    __syncthreads();
    for (int i = tid; i < BNODES; i += 256) {
        int n = node0 + i;
        if (n < NN) {
            row[n]  = s0 + off[i];
            dinv[n] = rsqrtf((float)cnt[i] + 1.0f);
        }
    }
    if (b == NB - 1 && tid == 0) row[NN] = NE;
    __syncthreads();
    for (int i = s0 + tid; i < s1; i += 256) {
        int2 p = part[i];
        int ln = p.y - node0;
        int pos = s0 + atomicAdd(&off[ln], 1);
        csr[pos] = p.x;
    }
}

// ================= layers =================

// layer1 gather, fused x@W1 + self-loop + bias + relu. 32 lanes per node.
__global__ void k_gather1(const int* __restrict__ row, const int* __restrict__ csr,
                          const float* __restrict__ x, const float* __restrict__ dinv,
                          const float* __restrict__ W1, const float* __restrict__ b1,
                          float* __restrict__ h) {
    int tid = threadIdx.x;
    int n = blockIdx.x * 8 + (tid >> 5);
    if (n >= NN) return;
    int f = tid & 31;
    float w0 = W1[0 * F + f], w1 = W1[1 * F + f], w2 = W1[2 * F + f];
    int beg = row[n], end = row[n + 1];
    float acc = 0.0f;
    int e = beg;
    for (; e + 3 < end; e += 4) {
        int s0 = csr[e], s1 = csr[e + 1], s2 = csr[e + 2], s3 = csr[e + 3];
        float d0 = dinv[s0], d1 = dinv[s1], d2 = dinv[s2], d3 = dinv[s3];
        float a0 = x[s0 * 3 + 0] * w0 + x[s0 * 3 + 1] * w1 + x[s0 * 3 + 2] * w2;
        float a1 = x[s1 * 3 + 0] * w0 + x[s1 * 3 + 1] * w1 + x[s1 * 3 + 2] * w2;
        float a2 = x[s2 * 3 + 0] * w0 + x[s2 * 3 + 1] * w1 + x[s2 * 3 + 2] * w2;
        float a3 = x[s3 * 3 + 0] * w0 + x[s3 * 3 + 1] * w1 + x[s3 * 3 + 2] * w2;
        acc += d0 * a0 + d1 * a1 + d2 * a2 + d3 * a3;
    }
    for (; e < end; ++e) {
        int sc = csr[e];
        float xv = x[sc * 3 + 0] * w0 + x[sc * 3 + 1] * w1 + x[sc * 3 + 2] * w2;
        acc += dinv[sc] * xv;
    }
    float dn = dinv[n];
    float self = x[n * 3 + 0] * w0 + x[n * 3 + 1] * w1 + x[n * 3 + 2] * w2;
    float v = dn * acc + self * (dn * dn) + b1[f];
    h[n * F + f] = fmaxf(v, 0.0f);
}

// xw2 = h @ W2
__global__ void k_xw2(const float* __restrict__ h, const float* __restrict__ W2,
                      float* __restrict__ xw) {
    __shared__ float Ws[F * F];
    __shared__ float hs[8][F];
    int tid = threadIdx.x;
    for (int i = tid; i < F * F; i += 256) Ws[i] = W2[i];
    int nl = tid >> 5, f = tid & 31;
    int n = blockIdx.x * 8 + nl;
    if (n < NN) hs[nl][f] = h[n * F + f];
    __syncthreads();
    if (n >= NN) return;
    float acc = 0.0f;
#pragma unroll
    for (int k = 0; k < F; k++) acc += hs[nl][k] * Ws[k * F + f];
    xw[n * F + f] = acc;
}

// layer2 gather + self-loop + bias + relu
__global__ void k_gather2(const int* __restrict__ row, const int* __restrict__ csr,
                          const float* __restrict__ xw, const float* __restrict__ dinv,
                          const float* __restrict__ b2, float* __restrict__ h) {
    int tid = threadIdx.x;
    int n = blockIdx.x * 8 + (tid >> 5);
    if (n >= NN) return;
    int f = tid & 31;
    int beg = row[n], end = row[n + 1];
    float acc = 0.0f;
    int e = beg;
    for (; e + 3 < end; e += 4) {
        int s0 = csr[e], s1 = csr[e + 1], s2 = csr[e + 2], s3 = csr[e + 3];
        float d0 = dinv[s0], d1 = dinv[s1], d2 = dinv[s2], d3 = dinv[s3];
        acc += d0 * xw[s0 * F + f] + d1 * xw[s1 * F + f]
             + d2 * xw[s2 * F + f] + d3 * xw[s3 * F + f];
    }
    for (; e < end; ++e) {
        int sc = csr[e];
        acc += dinv[sc] * xw[sc * F + f];
    }
    float dn = dinv[n];
    float v = dn * acc + xw[n * F + f] * (dn * dn) + b2[f];
    h[n * F + f] = fmaxf(v, 0.0f);
}

// ================= pool + head =================
__global__ void k_pool_head(const float* __restrict__ h, const int* __restrict__ batch,
                            const float* __restrict__ Wl, const float* __restrict__ bl,
                            float* __restrict__ out) {
    __shared__ float sum[8][F];
    __shared__ float mean[F];
    __shared__ int range[2];
    int g = blockIdx.x, tid = threadIdx.x;
    if (tid < 2) {
        int key = g + tid, lo = 0, hi = NN;
        while (lo < hi) {
            int mid = (lo + hi) >> 1;
            if (batch[mid] < key) lo = mid + 1; else hi = mid;
        }
        range[tid] = lo;
    }
    __syncthreads();
    int s = range[0], e = range[1];
    int grp = tid >> 5, f = tid & 31;
    float acc = 0.0f;
    for (int n = s + grp; n < e; n += 8) acc += h[n * F + f];
    sum[grp][f] = acc;
    __syncthreads();
    if (grp == 0) {
        float t = sum[0][f] + sum[1][f] + sum[2][f] + sum[3][f]
                + sum[4][f] + sum[5][f] + sum[6][f] + sum[7][f];
        mean[f] = t / fmaxf((float)(e - s), 1.0f);
    }
    __syncthreads();
    if (tid < 2) {
        float a = 0.0f;
#pragma unroll
        for (int k = 0; k < F; k++) a += mean[k] * Wl[k * 2 + tid];
        out[g * 2 + tid] = a + bl[tid];
    }
}

extern "C" void kernel_launch(void* const* d_in, const int* in_sizes, int n_in,
                              void* d_out, int out_size, void* d_ws, size_t ws_size,
                              hipStream_t stream) {
    const float* x     = (const float*)d_in[0];
    const int*   eidx  = (const int*)d_in[1];   // int32 per harness contract
    const int*   batch = (const int*)d_in[2];
    const float* W1    = (const float*)d_in[3];
    const float* b1    = (const float*)d_in[4];
    const float* W2    = (const float*)d_in[5];
    const float* b2    = (const float*)d_in[6];
    const float* Wl    = (const float*)d_in[7];
    const float* bl    = (const float*)d_in[8];
    float*       out   = (float*)d_out;

    const int* src = eidx;
    const int* dst = eidx + NE;

    // ---- workspace layout, 128B-aligned chunks ----
    char* base = (char*)d_ws;
    size_t off = 0;
    auto alloc = [&](size_t bytes) {
        void* p = base + off;
        off = (off + bytes + 127) & ~(size_t)127;
        return p;
    };
    int*   btot   = (int*)alloc(NB * sizeof(int));
    int*   bstart = (int*)alloc((NB + 1) * sizeof(int));
    int*   cursor = (int*)alloc(NB * sizeof(int));
    int*   row    = (int*)alloc((NN + 1) * sizeof(int));
    int*   csr    = (int*)alloc(NE * sizeof(int));
    float* dinv   = (float*)alloc(NN * sizeof(float));
    float* buf1   = (float*)alloc((size_t)NN * F * sizeof(float)); // also aliases part
    float* buf2   = (float*)alloc((size_t)NN * F * sizeof(float));
    int2*  part   = (int2*)buf1;   // NE int2 == NN*F floats; dead before k_xw2 writes buf1

    const int B = 256;
    const int gGath = (NN + 7) / 8;   // 12500

    // ---- CSR build: bucketed counting sort ----
    hipMemsetAsync(btot, 0, NB * sizeof(int), stream);
    k_count    <<<NWGE, B, 0, stream>>>(dst, btot);
    k_bscan    <<<1,    B, 0, stream>>>(btot, bstart, cursor);
    k_partition<<<NWGE, B, 0, stream>>>(src, dst, cursor, part);
    k_fill2    <<<NB,   B, 0, stream>>>(part, bstart, row, dinv, csr);

    // ---- layer 1 (fused transform+aggregate+epilogue) ----
    k_gather1<<<gGath, B, 0, stream>>>(row, csr, x, dinv, W1, b1, buf2);  // buf2 = h1

    // ---- layer 2 ----
    k_xw2    <<<gGath, B, 0, stream>>>(buf2, W2, buf1);                   // buf1 = h1@W2
    k_gather2<<<gGath, B, 0, stream>>>(row, csr, buf1, dinv, b2, buf2);   // buf2 = h2

    // ---- pool + head ----
    k_pool_head<<<NG, B, 0, stream>>>(buf2, batch, Wl, bl, out);
}

// Round 5
// 247.451 us; speedup vs baseline: 2.8902x; 1.1434x over previous
//
#include <hip/hip_runtime.h>

#define NN 100000
#define NE 1600000
#define NG 512
#define F  32

#define BSH    8                              // 256 dst-nodes per bucket
#define BNODES 256
#define NB     ((NN + BNODES - 1) / BNODES)   // 391
#define CHUNK  2048
#define NWGE   ((NE + CHUNK - 1) / CHUNK)     // 782

// ---- per-WG LDS histogram of dst buckets -> global bucket totals ----
__global__ void k_count(const int* __restrict__ dst, int* __restrict__ btot) {
    __shared__ int hist[NB];
    int tid = threadIdx.x;
    for (int i = tid; i < NB; i += 256) hist[i] = 0;
    __syncthreads();
    int e0 = blockIdx.x * CHUNK;
    int e1 = min(e0 + CHUNK, NE);
    for (int e = e0 + tid; e < e1; e += 256) atomicAdd(&hist[dst[e] >> BSH], 1);
    __syncthreads();
    for (int i = tid; i < NB; i += 256)
        if (hist[i]) atomicAdd(&btot[i], hist[i]);
}

// ---- scan bucket totals -> bucket_start[NB+1]; init cursors. one 512-block ----
__global__ void k_bscan(const int* __restrict__ btot, int* __restrict__ bstart,
                        int* __restrict__ cursor) {
    __shared__ int lds[512];
    int tid = threadIdx.x;
    int v = (tid < NB) ? btot[tid] : 0;
    lds[tid] = v;
    __syncthreads();
    for (int o = 1; o < 512; o <<= 1) {
        int t = (tid >= o) ? lds[tid - o] : 0;
        __syncthreads();
        lds[tid] += t;
        __syncthreads();
    }
    int excl = lds[tid] - v;
    if (tid < NB) { bstart[tid] = excl; cursor[tid] = excl; }
    if (tid == 0) bstart[NB] = NE;
}

// ---- partition edges into bucket-contiguous (src,dst) pairs ----
__global__ void k_partition(const int* __restrict__ src, const int* __restrict__ dst,
                            int* __restrict__ cursor, int2* __restrict__ part) {
    __shared__ int hist[NB];
    __shared__ int base[NB];
    int tid = threadIdx.x;
    for (int i = tid; i < NB; i += 256) hist[i] = 0;
    __syncthreads();
    int e0 = blockIdx.x * CHUNK;
    int e1 = min(e0 + CHUNK, NE);
    for (int e = e0 + tid; e < e1; e += 256) atomicAdd(&hist[dst[e] >> BSH], 1);
    __syncthreads();
    for (int i = tid; i < NB; i += 256) {
        base[i] = hist[i] ? atomicAdd(&cursor[i], hist[i]) : 0;
        hist[i] = 0;
    }
    __syncthreads();
    for (int e = e0 + tid; e < e1; e += 256) {
        int d = dst[e];
        int b = d >> BSH;
        int p = base[b] + atomicAdd(&hist[b], 1);
        part[p] = make_int2(src[e], d);
    }
}

// ---- per-bucket: histogram+scan -> row, dinv, xd; L2-local csr scatter ----
__global__ void k_fill2(const int2* __restrict__ part, const int* __restrict__ bstart,
                        const float* __restrict__ x,
                        int* __restrict__ row, float* __restrict__ dinv,
                        float4* __restrict__ xd, int* __restrict__ csr) {
    __shared__ int cnt[BNODES];
    __shared__ int off[BNODES];
    __shared__ int lds[BNODES];
    int b = blockIdx.x, tid = threadIdx.x;
    int node0 = b << BSH;
    int s0 = bstart[b], s1 = bstart[b + 1];
    cnt[tid] = 0;
    __syncthreads();
    for (int i = s0 + tid; i < s1; i += 256) atomicAdd(&cnt[part[i].y - node0], 1);
    __syncthreads();
    int c = cnt[tid];
    lds[tid] = c;
    __syncthreads();
    for (int o = 1; o < 256; o <<= 1) {
        int t = (tid >= o) ? lds[tid - o] : 0;
        __syncthreads();
        lds[tid] += t;
        __syncthreads();
    }
    int excl = lds[tid] - c;
    off[tid] = excl;
    int n = node0 + tid;
    if (n < NN) {
        row[n] = s0 + excl;
        float d = rsqrtf((float)c + 1.0f);
        dinv[n] = d;
        xd[n] = make_float4(d * x[n * 3 + 0], d * x[n * 3 + 1], d * x[n * 3 + 2], d);
    }
    if (b == NB - 1 && tid == 0) row[NN] = NE;
    __syncthreads();
    for (int i = s0 + tid; i < s1; i += 256) {
        int2 p = part[i];
        int pos = s0 + atomicAdd(&off[p.y - node0], 1);
        csr[pos] = p.x;
    }
}

// ================= layer 1 (projection pulled out of edge loop) =================

// per-node 3-vec aggregate: combine[n] = dinv[n]*(sum_e xd[src].xyz + xd[n].xyz)
__global__ void k_agg1(const int* __restrict__ row, const int* __restrict__ csr,
                       const float4* __restrict__ xd, float4* __restrict__ combine) {
    int n = blockIdx.x * blockDim.x + threadIdx.x;
    if (n >= NN) return;
    int beg = row[n], end = row[n + 1];
    float ax = 0.0f, ay = 0.0f, az = 0.0f;
    int e = beg;
    for (; e + 3 < end; e += 4) {
        int s0 = csr[e], s1 = csr[e + 1], s2 = csr[e + 2], s3 = csr[e + 3];
        float4 v0 = xd[s0], v1 = xd[s1], v2 = xd[s2], v3 = xd[s3];
        ax += (v0.x + v1.x) + (v2.x + v3.x);
        ay += (v0.y + v1.y) + (v2.y + v3.y);
        az += (v0.z + v1.z) + (v2.z + v3.z);
    }
    for (; e < end; ++e) {
        float4 v = xd[csr[e]];
        ax += v.x; ay += v.y; az += v.z;
    }
    float4 sf = xd[n];
    float dn = sf.w;
    combine[n] = make_float4(dn * (ax + sf.x), dn * (ay + sf.y), dn * (az + sf.z), 0.0f);
}

// h1 = relu(combine @ W1 + b1) — streaming
__global__ void k_proj1(const float4* __restrict__ combine, const float* __restrict__ W1,
                        const float* __restrict__ b1, float* __restrict__ h) {
    int idx = blockIdx.x * blockDim.x + threadIdx.x;
    if (idx >= NN * F) return;
    int n = idx >> 5, f = idx & 31;
    float4 c = combine[n];
    float v = c.x * W1[0 * F + f] + c.y * W1[1 * F + f] + c.z * W1[2 * F + f] + b1[f];
    h[idx] = fmaxf(v, 0.0f);
}

// ================= layer 2 =================

// xw2 = h @ W2
__global__ void k_xw2(const float* __restrict__ h, const float* __restrict__ W2,
                      float* __restrict__ xw) {
    __shared__ float Ws[F * F];
    __shared__ float hs[8][F];
    int tid = threadIdx.x;
    for (int i = tid; i < F * F; i += 256) Ws[i] = W2[i];
    int nl = tid >> 5, f = tid & 31;
    int n = blockIdx.x * 8 + nl;
    if (n < NN) hs[nl][f] = h[n * F + f];
    __syncthreads();
    if (n >= NN) return;
    float acc = 0.0f;
#pragma unroll
    for (int k = 0; k < F; k++) acc += hs[nl][k] * Ws[k * F + f];
    xw[n * F + f] = acc;
}

// gather + self-loop + bias + relu
__global__ void k_gather2(const int* __restrict__ row, const int* __restrict__ csr,
                          const float* __restrict__ xw, const float* __restrict__ dinv,
                          const float* __restrict__ b2, float* __restrict__ h) {
    int tid = threadIdx.x;
    int n = blockIdx.x * 8 + (tid >> 5);
    if (n >= NN) return;
    int f = tid & 31;
    int beg = row[n], end = row[n + 1];
    float acc = 0.0f;
    int e = beg;
    for (; e + 3 < end; e += 4) {
        int s0 = csr[e], s1 = csr[e + 1], s2 = csr[e + 2], s3 = csr[e + 3];
        float d0 = dinv[s0], d1 = dinv[s1], d2 = dinv[s2], d3 = dinv[s3];
        acc += d0 * xw[s0 * F + f] + d1 * xw[s1 * F + f]
             + d2 * xw[s2 * F + f] + d3 * xw[s3 * F + f];
    }
    for (; e < end; ++e) {
        int sc = csr[e];
        acc += dinv[sc] * xw[sc * F + f];
    }
    float dn = dinv[n];
    float v = dn * acc + xw[n * F + f] * (dn * dn) + b2[f];
    h[n * F + f] = fmaxf(v, 0.0f);
}

// ================= pool + head =================
__global__ void k_pool_head(const float* __restrict__ h, const int* __restrict__ batch,
                            const float* __restrict__ Wl, const float* __restrict__ bl,
                            float* __restrict__ out) {
    __shared__ float sum[8][F];
    __shared__ float mean[F];
    __shared__ int range[2];
    int g = blockIdx.x, tid = threadIdx.x;
    if (tid < 2) {
        int key = g + tid, lo = 0, hi = NN;
        while (lo < hi) {
            int mid = (lo + hi) >> 1;
            if (batch[mid] < key) lo = mid + 1; else hi = mid;
        }
        range[tid] = lo;
    }
    __syncthreads();
    int s = range[0], e = range[1];
    int grp = tid >> 5, f = tid & 31;
    float acc = 0.0f;
    for (int n = s + grp; n < e; n += 8) acc += h[n * F + f];
    sum[grp][f] = acc;
    __syncthreads();
    if (grp == 0) {
        float t = sum[0][f] + sum[1][f] + sum[2][f] + sum[3][f]
                + sum[4][f] + sum[5][f] + sum[6][f] + sum[7][f];
        mean[f] = t / fmaxf((float)(e - s), 1.0f);
    }
    __syncthreads();
    if (tid < 2) {
        float a = 0.0f;
#pragma unroll
        for (int k = 0; k < F; k++) a += mean[k] * Wl[k * 2 + tid];
        out[g * 2 + tid] = a + bl[tid];
    }
}

extern "C" void kernel_launch(void* const* d_in, const int* in_sizes, int n_in,
                              void* d_out, int out_size, void* d_ws, size_t ws_size,
                              hipStream_t stream) {
    const float* x     = (const float*)d_in[0];
    const int*   eidx  = (const int*)d_in[1];   // int32 per harness contract
    const int*   batch = (const int*)d_in[2];
    const float* W1    = (const float*)d_in[3];
    const float* b1    = (const float*)d_in[4];
    const float* W2    = (const float*)d_in[5];
    const float* b2    = (const float*)d_in[6];
    const float* Wl    = (const float*)d_in[7];
    const float* bl    = (const float*)d_in[8];
    float*       out   = (float*)d_out;

    const int* src = eidx;
    const int* dst = eidx + NE;

    // ---- workspace layout, 128B-aligned chunks ----
    char* base = (char*)d_ws;
    size_t off = 0;
    auto alloc = [&](size_t bytes) {
        void* p = base + off;
        off = (off + bytes + 127) & ~(size_t)127;
        return p;
    };
    int*    btot   = (int*)alloc(NB * sizeof(int));
    int*    bstart = (int*)alloc((NB + 1) * sizeof(int));
    int*    cursor = (int*)alloc(NB * sizeof(int));
    int*    row    = (int*)alloc((NN + 1) * sizeof(int));
    int*    csr    = (int*)alloc(NE * sizeof(int));
    float*  dinv   = (float*)alloc(NN * sizeof(float));
    float4* xd     = (float4*)alloc(NN * sizeof(float4));
    float*  buf1   = (float*)alloc((size_t)NN * F * sizeof(float));
    float*  buf2   = (float*)alloc((size_t)NN * F * sizeof(float));
    int2*   part   = (int2*)buf1;     // NE int2 == NN*F floats; dead before k_xw2 writes buf1
    float4* combine= (float4*)buf2;   // consumed by k_proj1 before... (see below)

    // NOTE: combine must NOT alias buf2 (k_proj1 writes h1 into buf2 while reading
    // combine). Give combine its own slice instead:
    combine = (float4*)alloc(NN * sizeof(float4));

    const int B = 256;
    const int gNF  = (NN * F + B - 1) / B;   // 12500
    const int gN   = (NN + B - 1) / B;       // 391
    const int gGath = (NN + 7) / 8;          // 12500

    // ---- CSR build: bucketed counting sort ----
    hipMemsetAsync(btot, 0, NB * sizeof(int), stream);
    k_count    <<<NWGE, B, 0, stream>>>(dst, btot);
    k_bscan    <<<1,  512, 0, stream>>>(btot, bstart, cursor);
    k_partition<<<NWGE, B, 0, stream>>>(src, dst, cursor, part);
    k_fill2    <<<NB,   B, 0, stream>>>(part, bstart, x, row, dinv, xd, csr);

    // ---- layer 1: 3-dim aggregate then project ----
    k_agg1 <<<gN,  B, 0, stream>>>(row, csr, xd, combine);
    k_proj1<<<gNF, B, 0, stream>>>(combine, W1, b1, buf2);        // buf2 = h1

    // ---- layer 2 ----
    k_xw2    <<<gGath, B, 0, stream>>>(buf2, W2, buf1);           // buf1 = h1@W2 (kills part)
    k_gather2<<<gGath, B, 0, stream>>>(row, csr, buf1, dinv, b2, buf2); // buf2 = h2

    // ---- pool + head ----
    k_pool_head<<<NG, B, 0, stream>>>(buf2, batch, Wl, bl, out);
}

// Round 6
// 213.720 us; speedup vs baseline: 3.3464x; 1.1578x over previous
//
#include <hip/hip_runtime.h>
#include <hip/hip_fp16.h>

#define NN 100000
#define NE 1600000
#define NG 512
#define F  32

#define BSH    8                              // 256 dst-nodes per bucket
#define BNODES 256
#define NB     ((NN + BNODES - 1) / BNODES)   // 391
#define CCHUNK 2048
#define NWGC   ((NE + CCHUNK - 1) / CCHUNK)   // 782 (count)
#define PCHUNK 4096
#define NWGP   ((NE + PCHUNK - 1) / PCHUNK)   // 391 (partition)

// ---- per-WG LDS histogram of dst buckets -> global bucket totals ----
__global__ void k_count(const int* __restrict__ dst, int* __restrict__ btot) {
    __shared__ int hist[NB];
    int tid = threadIdx.x;
    for (int i = tid; i < NB; i += 256) hist[i] = 0;
    __syncthreads();
    int e0 = blockIdx.x * CCHUNK;
    int e1 = min(e0 + CCHUNK, NE);
    for (int e = e0 + tid; e < e1; e += 256) atomicAdd(&hist[dst[e] >> BSH], 1);
    __syncthreads();
    for (int i = tid; i < NB; i += 256)
        if (hist[i]) atomicAdd(&btot[i], hist[i]);
}

// ---- scan bucket totals -> bucket_start[NB+1]; init cursors. one 512-block ----
__global__ void k_bscan(const int* __restrict__ btot, int* __restrict__ bstart,
                        int* __restrict__ cursor) {
    __shared__ int lds[512];
    int tid = threadIdx.x;
    int v = (tid < NB) ? btot[tid] : 0;
    lds[tid] = v;
    __syncthreads();
    for (int o = 1; o < 512; o <<= 1) {
        int t = (tid >= o) ? lds[tid - o] : 0;
        __syncthreads();
        lds[tid] += t;
        __syncthreads();
    }
    int excl = lds[tid] - v;
    if (tid < NB) { bstart[tid] = excl; cursor[tid] = excl; }
    if (tid == 0) bstart[NB] = NE;
}

// ---- partition edges into bucket-contiguous (src,dst) pairs. WG=512 ----
__global__ void k_partition(const int* __restrict__ src, const int* __restrict__ dst,
                            int* __restrict__ cursor, int2* __restrict__ part) {
    __shared__ int hist[NB];
    __shared__ int base[NB];
    int tid = threadIdx.x;
    for (int i = tid; i < NB; i += 512) hist[i] = 0;
    __syncthreads();
    int e0 = blockIdx.x * PCHUNK;
    int e1 = min(e0 + PCHUNK, NE);
    for (int e = e0 + tid; e < e1; e += 512) atomicAdd(&hist[dst[e] >> BSH], 1);
    __syncthreads();
    for (int i = tid; i < NB; i += 512) {
        base[i] = hist[i] ? atomicAdd(&cursor[i], hist[i]) : 0;
        hist[i] = 0;
    }
    __syncthreads();
    for (int e = e0 + tid; e < e1; e += 512) {
        int d = dst[e];
        int b = d >> BSH;
        int p = base[b] + atomicAdd(&hist[b], 1);
        part[p] = make_int2(src[e], d);
    }
}

// ---- per-bucket: histogram+scan -> row, dinv, xd; L2-local csr scatter ----
__global__ void k_fill2(const int2* __restrict__ part, const int* __restrict__ bstart,
                        const float* __restrict__ x,
                        int* __restrict__ row, float* __restrict__ dinv,
                        float4* __restrict__ xd, int* __restrict__ csr) {
    __shared__ int cnt[BNODES];
    __shared__ int off[BNODES];
    __shared__ int lds[BNODES];
    int b = blockIdx.x, tid = threadIdx.x;
    int node0 = b << BSH;
    int s0 = bstart[b], s1 = bstart[b + 1];
    cnt[tid] = 0;
    __syncthreads();
    for (int i = s0 + tid; i < s1; i += 256) atomicAdd(&cnt[part[i].y - node0], 1);
    __syncthreads();
    int c = cnt[tid];
    lds[tid] = c;
    __syncthreads();
    for (int o = 1; o < 256; o <<= 1) {
        int t = (tid >= o) ? lds[tid - o] : 0;
        __syncthreads();
        lds[tid] += t;
        __syncthreads();
    }
    int excl = lds[tid] - c;
    off[tid] = excl;
    int n = node0 + tid;
    if (n < NN) {
        row[n] = s0 + excl;
        float d = rsqrtf((float)c + 1.0f);
        dinv[n] = d;
        xd[n] = make_float4(d * x[n * 3 + 0], d * x[n * 3 + 1], d * x[n * 3 + 2], d);
    }
    if (b == NB - 1 && tid == 0) row[NN] = NE;
    __syncthreads();
    for (int i = s0 + tid; i < s1; i += 256) {
        int2 p = part[i];
        int pos = s0 + atomicAdd(&off[p.y - node0], 1);
        csr[pos] = p.x;
    }
}

// ================= layer 1 =================

// per-node 3-vec aggregate: combine[n] = dinv[n]*(sum_e xd[src].xyz + xd[n].xyz)
__global__ void k_agg1(const int* __restrict__ row, const int* __restrict__ csr,
                       const float4* __restrict__ xd, float4* __restrict__ combine) {
    int n = blockIdx.x * blockDim.x + threadIdx.x;
    if (n >= NN) return;
    int beg = row[n], end = row[n + 1];
    float ax = 0.0f, ay = 0.0f, az = 0.0f;
    int e = beg;
    for (; e + 3 < end; e += 4) {
        int s0 = csr[e], s1 = csr[e + 1], s2 = csr[e + 2], s3 = csr[e + 3];
        float4 v0 = xd[s0], v1 = xd[s1], v2 = xd[s2], v3 = xd[s3];
        ax += (v0.x + v1.x) + (v2.x + v3.x);
        ay += (v0.y + v1.y) + (v2.y + v3.y);
        az += (v0.z + v1.z) + (v2.z + v3.z);
    }
    for (; e < end; ++e) {
        float4 v = xd[csr[e]];
        ax += v.x; ay += v.y; az += v.z;
    }
    float4 sf = xd[n];
    float dn = sf.w;
    combine[n] = make_float4(dn * (ax + sf.x), dn * (ay + sf.y), dn * (az + sf.z), 0.0f);
}

// h1 = relu(combine @ W1 + b1), packed half2. one thread per feature-pair.
__global__ void k_proj1(const float4* __restrict__ combine, const float* __restrict__ W1,
                        const float* __restrict__ b1, __half2* __restrict__ h1) {
    int idx = blockIdx.x * blockDim.x + threadIdx.x;
    if (idx >= NN * 16) return;
    int n = idx >> 4, j = idx & 15;
    float4 c = combine[n];
    int f0 = 2 * j, f1 = 2 * j + 1;
    float v0 = c.x * W1[0 * F + f0] + c.y * W1[1 * F + f0] + c.z * W1[2 * F + f0] + b1[f0];
    float v1 = c.x * W1[0 * F + f1] + c.y * W1[1 * F + f1] + c.z * W1[2 * F + f1] + b1[f1];
    h1[idx] = __floats2half2_rn(fmaxf(v0, 0.0f), fmaxf(v1, 0.0f));
}

// ================= layer 2 =================
// t[n] = dn*sum_e dinv[s]*h1[s] + dn^2*h1[n]   (W2 applied later — linearity)
// 16 lanes per node, half2 payload (64 B/node row).
__global__ void k_gather2h(const int* __restrict__ row, const int* __restrict__ csr,
                           const __half2* __restrict__ h1, const float* __restrict__ dinv,
                           __half2* __restrict__ t16) {
    int tid = threadIdx.x;
    int n = blockIdx.x * 16 + (tid >> 4);
    if (n >= NN) return;
    int j = tid & 15;
    int beg = row[n], end = row[n + 1];
    float ax = 0.0f, ay = 0.0f;
    int e = beg;
    for (; e + 3 < end; e += 4) {
        int s0 = csr[e], s1 = csr[e + 1], s2 = csr[e + 2], s3 = csr[e + 3];
        float d0 = dinv[s0], d1 = dinv[s1], d2 = dinv[s2], d3 = dinv[s3];
        float2 v0 = __half22float2(h1[s0 * 16 + j]);
        float2 v1 = __half22float2(h1[s1 * 16 + j]);
        float2 v2 = __half22float2(h1[s2 * 16 + j]);
        float2 v3 = __half22float2(h1[s3 * 16 + j]);
        ax += d0 * v0.x + d1 * v1.x + d2 * v2.x + d3 * v3.x;
        ay += d0 * v0.y + d1 * v1.y + d2 * v2.y + d3 * v3.y;
    }
    for (; e < end; ++e) {
        int s = csr[e];
        float d = dinv[s];
        float2 v = __half22float2(h1[s * 16 + j]);
        ax += d * v.x;
        ay += d * v.y;
    }
    float dn = dinv[n];
    float2 sf = __half22float2(h1[n * 16 + j]);
    float tx = dn * ax + dn * dn * sf.x;
    float ty = dn * ay + dn * dn * sf.y;
    t16[n * 16 + j] = __floats2half2_rn(tx, ty);
}

// ================= fused proj2 + relu + pool + head =================
// one block per graph; h2 = relu(t@W2+b2) computed on the fly, mean-pooled, head.
__global__ void k_proj2_pool_head(const __half2* __restrict__ t16,
                                  const int* __restrict__ batch,
                                  const float* __restrict__ W2, const float* __restrict__ b2,
                                  const float* __restrict__ Wl, const float* __restrict__ bl,
                                  float* __restrict__ out) {
    __shared__ float W2s[F * F];
    __shared__ float ts[8][F];
    __shared__ float red[8][F];
    __shared__ float mean[F];
    __shared__ int range[2];
    int g = blockIdx.x, tid = threadIdx.x;
    for (int i = tid; i < F * F; i += 256) W2s[i] = W2[i];
    if (tid < 2) {
        int key = g + tid, lo = 0, hi = NN;
        while (lo < hi) {
            int mid = (lo + hi) >> 1;
            if (batch[mid] < key) lo = mid + 1; else hi = mid;
        }
        range[tid] = lo;
    }
    __syncthreads();
    int s = range[0], e = range[1];
    int grp = tid >> 5, f = tid & 31;
    float b2f = b2[f];
    float psum = 0.0f;
    for (int n0 = s; n0 < e; n0 += 8) {
        __syncthreads();
        if (tid < 128) {
            int nl = tid >> 4, j = tid & 15;
            int n = n0 + nl;
            if (n < e) {
                float2 v = __half22float2(t16[n * 16 + j]);
                ts[nl][2 * j]     = v.x;
                ts[nl][2 * j + 1] = v.y;
            }
        }
        __syncthreads();
        int n = n0 + grp;
        if (n < e) {
            float acc = b2f;
#pragma unroll
            for (int k = 0; k < F; k++) acc += ts[grp][k] * W2s[k * F + f];
            psum += fmaxf(acc, 0.0f);
        }
    }
    red[grp][f] = psum;
    __syncthreads();
    if (grp == 0) {
        float t = red[0][f] + red[1][f] + red[2][f] + red[3][f]
                + red[4][f] + red[5][f] + red[6][f] + red[7][f];
        mean[f] = t / fmaxf((float)(e - s), 1.0f);
    }
    __syncthreads();
    if (tid < 2) {
        float a = 0.0f;
#pragma unroll
        for (int k = 0; k < F; k++) a += mean[k] * Wl[k * 2 + tid];
        out[g * 2 + tid] = a + bl[tid];
    }
}

extern "C" void kernel_launch(void* const* d_in, const int* in_sizes, int n_in,
                              void* d_out, int out_size, void* d_ws, size_t ws_size,
                              hipStream_t stream) {
    const float* x     = (const float*)d_in[0];
    const int*   eidx  = (const int*)d_in[1];   // int32 per harness contract
    const int*   batch = (const int*)d_in[2];
    const float* W1    = (const float*)d_in[3];
    const float* b1    = (const float*)d_in[4];
    const float* W2    = (const float*)d_in[5];
    const float* b2    = (const float*)d_in[6];
    const float* Wl    = (const float*)d_in[7];
    const float* bl    = (const float*)d_in[8];
    float*       out   = (float*)d_out;

    const int* src = eidx;
    const int* dst = eidx + NE;

    // ---- workspace layout, 128B-aligned chunks ----
    char* base = (char*)d_ws;
    size_t off = 0;
    auto alloc = [&](size_t bytes) {
        void* p = base + off;
        off = (off + bytes + 127) & ~(size_t)127;
        return p;
    };
    int*     btot    = (int*)alloc(NB * sizeof(int));
    int*     bstart  = (int*)alloc((NB + 1) * sizeof(int));
    int*     cursor  = (int*)alloc(NB * sizeof(int));
    int*     row     = (int*)alloc((NN + 1) * sizeof(int));
    int*     csr     = (int*)alloc(NE * sizeof(int));
    float*   dinv    = (float*)alloc(NN * sizeof(float));
    float4*  xd      = (float4*)alloc(NN * sizeof(float4));
    float4*  combine = (float4*)alloc(NN * sizeof(float4));
    int2*    part    = (int2*)alloc((size_t)NE * sizeof(int2));   // dead after k_fill2
    __half2* h1      = (__half2*)alloc((size_t)NN * 16 * sizeof(__half2));
    __half2* t16     = (__half2*)alloc((size_t)NN * 16 * sizeof(__half2));

    const int B = 256;
    const int gN   = (NN + B - 1) / B;            // 391
    const int gNH  = (NN * 16 + B - 1) / B;       // 6250
    const int gG16 = (NN + 15) / 16;              // 6250

    // ---- CSR build: bucketed counting sort ----
    hipMemsetAsync(btot, 0, NB * sizeof(int), stream);
    k_count    <<<NWGC, B,   0, stream>>>(dst, btot);
    k_bscan    <<<1,    512, 0, stream>>>(btot, bstart, cursor);
    k_partition<<<NWGP, 512, 0, stream>>>(src, dst, cursor, part);
    k_fill2    <<<NB,   B,   0, stream>>>(part, bstart, x, row, dinv, xd, csr);

    // ---- layer 1: 3-dim aggregate then project (h1 in fp16) ----
    k_agg1 <<<gN,  B, 0, stream>>>(row, csr, xd, combine);
    k_proj1<<<gNH, B, 0, stream>>>(combine, W1, b1, h1);

    // ---- layer 2: gather h1 (fp16 payload), W2 deferred ----
    k_gather2h<<<gG16, B, 0, stream>>>(row, csr, h1, dinv, t16);

    // ---- fused proj2 + relu + pool + head ----
    k_proj2_pool_head<<<NG, B, 0, stream>>>(t16, batch, W2, b2, Wl, bl, out);
}